// Round 7
// baseline (1951.732 us; speedup 1.0000x reference)
//
#include <hip/hip_runtime.h>
#include <hip/hip_fp16.h>

#define B_  32
#define T_  2048
#define I_  256
#define H_  128

typedef _Float16 f16;
typedef _Float16 f16x2 __attribute__((ext_vector_type(2)));
typedef _Float16 f16x4 __attribute__((ext_vector_type(4)));
typedef _Float16 f16x8 __attribute__((ext_vector_type(8)));
typedef float    f32x4 __attribute__((ext_vector_type(4)));

#if __has_builtin(__builtin_amdgcn_fdot2)
#define FDOT2(a, b, c) __builtin_amdgcn_fdot2((a), (b), (c), false)
#else
static __device__ __forceinline__ float FDOT2(f16x2 a, f16x2 b, float c) {
  return c + (float)a[0] * (float)b[0] + (float)a[1] * (float)b[1];
}
#endif

static __device__ __forceinline__ f16x2 asf16x2(unsigned u) {
  return __builtin_bit_cast(f16x2, u);
}

// sigmoid(x) = 1/(1+2^(-x*log2e));  tanh(x) = 2*sig(2x)-1
static __device__ __forceinline__ float fast_sig(float x) {
  float e = __builtin_amdgcn_exp2f(-1.44269504089f * x);
  return __builtin_amdgcn_rcpf(1.0f + e);
}
static __device__ __forceinline__ float fast_tanh(float x) {
  float e = __builtin_amdgcn_exp2f(-2.88539008178f * x);
  return 2.0f * __builtin_amdgcn_rcpf(1.0f + e) - 1.0f;
}

// LDS-only barrier: do NOT drain vmcnt -- global prefetch loads and out[]
// stores float across steps.  sched_barrier(0) fences per rule #18.
#define BARRIER_LDS()                                   \
  __builtin_amdgcn_sched_barrier(0);                    \
  asm volatile("s_waitcnt lgkmcnt(0)" ::: "memory");    \
  __builtin_amdgcn_s_barrier();                         \
  __builtin_amdgcn_sched_barrier(0)

#define MFMA16(a, b, c) __builtin_amdgcn_mfma_f32_16x16x32_f16((a), (b), (c), 0, 0, 0)

// ---------------------------------------------------------------------------
// Kernel 1: xg[m][col] with GATE-INTERLEAVED layout:
//   col = dir*512 + unit*4 + gate   (gate: 0=i 1=f 2=g 3=o, unit in [0,128))
//   value = x[m]·W_ih[row] + b_ih[row] + b_hh[row],  row = gate*128+unit.
//   Interleaving lets the recurrence fetch a unit's 4 gates as one 8B load.
// ---------------------------------------------------------------------------
__global__ __launch_bounds__(256) void xg_gemm(
    const float* __restrict__ x,
    const float* __restrict__ Wf, const float* __restrict__ Wb,
    const float* __restrict__ bf_ih, const float* __restrict__ bf_hh,
    const float* __restrict__ bb_ih, const float* __restrict__ bb_hh,
    f16* __restrict__ xg)
{
  __shared__ f16 xs[128][136];   // +8 f16 pad
  __shared__ f16 wt[128][136];

  const int tid = threadIdx.x;
  const int m0  = blockIdx.y * 128;
  const int n0  = blockIdx.x * 128;

  const float* Wsrc; const float* bih; const float* bhh; int nb; size_t dbase;
  if (n0 < 512) { Wsrc = Wf; bih = bf_ih; bhh = bf_hh; nb = n0;       dbase = 0; }
  else          { Wsrc = Wb; bih = bb_ih; bhh = bb_hh; nb = n0 - 512; dbase = 512; }

  const int w  = tid >> 6;
  const int l  = tid & 63;
  const int lr = l & 15;
  const int lk = (l >> 4) * 8;

  f32x4 acc[2][8] = {};

  #pragma unroll
  for (int kh = 0; kh < 2; ++kh) {
    #pragma unroll
    for (int it = 0; it < 16; ++it) {
      int idx = it * 256 + tid;
      int row = idx >> 5, c4 = idx & 31;
      float4 v = *(const float4*)&x[(size_t)(m0 + row) * I_ + kh * 128 + c4 * 4];
      f16x4 h4 = { (f16)v.x, (f16)v.y, (f16)v.z, (f16)v.w };
      *(f16x4*)&xs[row][c4 * 4] = h4;
    }
    #pragma unroll
    for (int it = 0; it < 16; ++it) {
      int idx = it * 256 + tid;
      int row = idx >> 5, c4 = idx & 31;
      float4 v = *(const float4*)&Wsrc[(size_t)(nb + row) * I_ + kh * 128 + c4 * 4];
      f16x4 h4 = { (f16)v.x, (f16)v.y, (f16)v.z, (f16)v.w };
      *(f16x4*)&wt[row][c4 * 4] = h4;
    }
    __syncthreads();

    #pragma unroll
    for (int ks = 0; ks < 4; ++ks) {
      int kk = ks * 32 + lk;
      f16x8 a0 = *(const f16x8*)&xs[w * 32 + lr][kk];
      f16x8 a1 = *(const f16x8*)&xs[w * 32 + 16 + lr][kk];
      #pragma unroll
      for (int nt = 0; nt < 8; ++nt) {
        f16x8 bf = *(const f16x8*)&wt[nt * 16 + lr][kk];
        acc[0][nt] = MFMA16(a0, bf, acc[0][nt]);
        acc[1][nt] = MFMA16(a1, bf, acc[1][nt]);
      }
    }
    __syncthreads();
  }

  // epilogue: D row = (l>>4)*4 + r, col = l&15; scatter to interleaved layout
  #pragma unroll
  for (int mt = 0; mt < 2; ++mt) {
    #pragma unroll
    for (int nt = 0; nt < 8; ++nt) {
      int nloc = nt * 16 + lr;
      int grow = nb + nloc;                 // gate-row within dir, 0..511
      int gate = grow >> 7, unit = grow & 127;
      size_t col = dbase + (size_t)unit * 4 + gate;
      float bias = bih[grow] + bhh[grow];
      #pragma unroll
      for (int r = 0; r < 4; ++r) {
        int m = m0 + w * 32 + mt * 16 + (l >> 4) * 4 + r;
        xg[(size_t)m * 1024 + col] = (f16)(acc[mt][nt][r] + bias);
      }
    }
  }
}

// ---------------------------------------------------------------------------
// Kernel 2: recurrence, minimal-broadcast layout.
//   64 WGs x 1024 thr (16 waves, 4 waves/SIMD).  Wave w, lane l:
//     unit u = w*8 + ((l>>2)&7)          (one FULL unit: rows i,f,g,o)
//     ks    = (l&3) | ((l>>5)<<2)        (K-slice [ks*16, ks*16+16))
//   Weights: 4 rows x 16 cols = 32 f16x2 words/thread (VGPR-resident).
//   Per step/thread: 2 ds_read_b128 (32B of h -> 32KB/CU, half of R6),
//   32 v_dot2, K-reduce via shfl_xor 1,2 (DPP) + 32 (permlane) -- no LDS.
//   xg: unit's 4 gates = one 8B load (interleaved layout), prefetch dist 4.
//   ks==0 lanes write h (f16) and out.  ONE LDS-only barrier per step.
// ---------------------------------------------------------------------------
__global__ __launch_bounds__(1024, 4) void birnn_rec(
    const f16* __restrict__ xg,
    const float* __restrict__ Wfhh, const float* __restrict__ Wbhh,
    const int* __restrict__ lengths,
    float* __restrict__ out)
{
  const int tid = threadIdx.x;
  const int w   = tid >> 6;
  const int l   = tid & 63;
  const int ks  = (l & 3) | ((l >> 5) << 2);   // 0..7
  const int u   = w * 8 + ((l >> 2) & 7);      // 0..127
  const int dir = blockIdx.x >> 5;
  const int b   = blockIdx.x & 31;
  const float* Whh = dir ? Wbhh : Wfhh;
  const int L   = lengths[b];

  // weights: wrg[g][j] = W_hh[g*128+u][ks*16 + 2j .. 2j+1]  (fully unrolled)
  unsigned wrg[4][8];
  #pragma unroll
  for (int g = 0; g < 4; ++g) {
    const float* src = &Whh[(size_t)(g * 128 + u) * H_ + ks * 16];
    #pragma unroll
    for (int j = 0; j < 4; ++j) {
      float4 v = *(const float4*)&src[j * 4];
      wrg[g][2 * j]     = __builtin_bit_cast(unsigned, (f16x2){ (f16)v.x, (f16)v.y });
      wrg[g][2 * j + 1] = __builtin_bit_cast(unsigned, (f16x2){ (f16)v.z, (f16)v.w });
    }
  }

  __shared__ __align__(16) f16 hbuf[2][128];
  if (tid < 128) hbuf[0][tid] = (f16)0.0f;
  float c = 0.0f;
  __syncthreads();

  auto rowof = [&](int t) -> size_t {
    int it = t;
    if (dir) it = (t < L) ? (L - 1 - t) : t;
    return ((size_t)(b * T_ + it)) * 1024 + (size_t)dir * 512 + (size_t)u * 4;
  };

  // 4-slot prefetch ring (named slots; distance 4 steps ~ 1 us >> HBM latency)
  uint2 pa = *(const uint2*)(xg + rowof(0));
  uint2 pb = *(const uint2*)(xg + rowof(1));
  uint2 pc = *(const uint2*)(xg + rowof(2));
  uint2 pd = *(const uint2*)(xg + rowof(3));

  const bool writer = (ks == 0);

#define STEP(t, P, RB, WB)                                                   \
  {                                                                          \
    f16x4 xv = __builtin_bit_cast(f16x4, P);                                 \
    if ((t) + 4 < T_) P = *(const uint2*)(xg + rowof((t) + 4));              \
    uint4 hva = *(const uint4*)&hbuf[RB][ks * 16];                           \
    uint4 hvb = *(const uint4*)&hbuf[RB][ks * 16 + 8];                       \
    float ai = 0.f, af = 0.f, ag = 0.f, ao = 0.f;                            \
    ai = FDOT2(asf16x2(hva.x), asf16x2(wrg[0][0]), ai);                      \
    af = FDOT2(asf16x2(hva.x), asf16x2(wrg[1][0]), af);                      \
    ag = FDOT2(asf16x2(hva.x), asf16x2(wrg[2][0]), ag);                      \
    ao = FDOT2(asf16x2(hva.x), asf16x2(wrg[3][0]), ao);                      \
    ai = FDOT2(asf16x2(hva.y), asf16x2(wrg[0][1]), ai);                      \
    af = FDOT2(asf16x2(hva.y), asf16x2(wrg[1][1]), af);                      \
    ag = FDOT2(asf16x2(hva.y), asf16x2(wrg[2][1]), ag);                      \
    ao = FDOT2(asf16x2(hva.y), asf16x2(wrg[3][1]), ao);                      \
    ai = FDOT2(asf16x2(hva.z), asf16x2(wrg[0][2]), ai);                      \
    af = FDOT2(asf16x2(hva.z), asf16x2(wrg[1][2]), af);                      \
    ag = FDOT2(asf16x2(hva.z), asf16x2(wrg[2][2]), ag);                      \
    ao = FDOT2(asf16x2(hva.z), asf16x2(wrg[3][2]), ao);                      \
    ai = FDOT2(asf16x2(hva.w), asf16x2(wrg[0][3]), ai);                      \
    af = FDOT2(asf16x2(hva.w), asf16x2(wrg[1][3]), af);                      \
    ag = FDOT2(asf16x2(hva.w), asf16x2(wrg[2][3]), ag);                      \
    ao = FDOT2(asf16x2(hva.w), asf16x2(wrg[3][3]), ao);                      \
    ai = FDOT2(asf16x2(hvb.x), asf16x2(wrg[0][4]), ai);                      \
    af = FDOT2(asf16x2(hvb.x), asf16x2(wrg[1][4]), af);                      \
    ag = FDOT2(asf16x2(hvb.x), asf16x2(wrg[2][4]), ag);                      \
    ao = FDOT2(asf16x2(hvb.x), asf16x2(wrg[3][4]), ao);                      \
    ai = FDOT2(asf16x2(hvb.y), asf16x2(wrg[0][5]), ai);                      \
    af = FDOT2(asf16x2(hvb.y), asf16x2(wrg[1][5]), af);                      \
    ag = FDOT2(asf16x2(hvb.y), asf16x2(wrg[2][5]), ag);                      \
    ao = FDOT2(asf16x2(hvb.y), asf16x2(wrg[3][5]), ao);                      \
    ai = FDOT2(asf16x2(hvb.z), asf16x2(wrg[0][6]), ai);                      \
    af = FDOT2(asf16x2(hvb.z), asf16x2(wrg[1][6]), af);                      \
    ag = FDOT2(asf16x2(hvb.z), asf16x2(wrg[2][6]), ag);                      \
    ao = FDOT2(asf16x2(hvb.z), asf16x2(wrg[3][6]), ao);                      \
    ai = FDOT2(asf16x2(hvb.w), asf16x2(wrg[0][7]), ai);                      \
    af = FDOT2(asf16x2(hvb.w), asf16x2(wrg[1][7]), af);                      \
    ag = FDOT2(asf16x2(hvb.w), asf16x2(wrg[2][7]), ag);                      \
    ao = FDOT2(asf16x2(hvb.w), asf16x2(wrg[3][7]), ao);                      \
    /* K-reduce over 8 slices: lane bits 0,1 (DPP) + 5 (permlane) */         \
    ai += __shfl_xor(ai, 1, 64);  af += __shfl_xor(af, 1, 64);               \
    ag += __shfl_xor(ag, 1, 64);  ao += __shfl_xor(ao, 1, 64);               \
    ai += __shfl_xor(ai, 2, 64);  af += __shfl_xor(af, 2, 64);               \
    ag += __shfl_xor(ag, 2, 64);  ao += __shfl_xor(ao, 2, 64);               \
    ai += __shfl_xor(ai, 32, 64); af += __shfl_xor(af, 32, 64);              \
    ag += __shfl_xor(ag, 32, 64); ao += __shfl_xor(ao, 32, 64);              \
    float is = fast_sig(ai + (float)xv[0]);                                  \
    float fs = fast_sig(af + (float)xv[1]);                                  \
    float gt = fast_tanh(ag + (float)xv[2]);                                 \
    float os = fast_sig(ao + (float)xv[3]);                                  \
    c = fs * c + is * gt;                                                    \
    float hval = os * fast_tanh(c);                                          \
    if (writer) {                                                            \
      hbuf[WB][u] = (f16)hval;                                               \
      out[((size_t)(b * T_ + (t))) * 256 + dir * 128 + u] = hval;            \
    }                                                                        \
    BARRIER_LDS();                                                           \
  }

  for (int tt = 0; tt < T_; tt += 4) {
    STEP(tt,     pa, 0, 1);
    STEP(tt + 1, pb, 1, 0);
    STEP(tt + 2, pc, 0, 1);
    STEP(tt + 3, pd, 1, 0);
  }
#undef STEP
}

// ---------------------------------------------------------------------------
extern "C" void kernel_launch(void* const* d_in, const int* in_sizes, int n_in,
                              void* d_out, int out_size, void* d_ws, size_t ws_size,
                              hipStream_t stream) {
  const float* x      = (const float*)d_in[0];
  const int*   lengths= (const int*)  d_in[1];
  const float* Wf_ih  = (const float*)d_in[2];
  const float* Wf_hh  = (const float*)d_in[3];
  const float* bf_ih  = (const float*)d_in[4];
  const float* bf_hh  = (const float*)d_in[5];
  const float* Wb_ih  = (const float*)d_in[6];
  const float* Wb_hh  = (const float*)d_in[7];
  const float* bb_ih  = (const float*)d_in[8];
  const float* bb_hh  = (const float*)d_in[9];
  float* out = (float*)d_out;
  f16*   xg  = (f16*)d_ws;   // needs B*T*1024*2 = 134,217,728 bytes

  (void)in_sizes; (void)n_in; (void)out_size; (void)ws_size;

  xg_gemm<<<dim3(8, 512), 256, 0, stream>>>(x, Wf_ih, Wb_ih,
                                            bf_ih, bf_hh, bb_ih, bb_hh, xg);
  birnn_rec<<<dim3(64), 1024, 0, stream>>>(xg, Wf_hh, Wb_hh, lengths, out);
}

// Round 9
// 1400.498 us; speedup vs baseline: 1.3936x; 1.3936x over previous
//
#include <hip/hip_runtime.h>
#include <hip/hip_fp16.h>

#define B_  32
#define T_  2048
#define I_  256
#define H_  128

typedef _Float16 f16;
typedef _Float16 f16x2 __attribute__((ext_vector_type(2)));
typedef _Float16 f16x4 __attribute__((ext_vector_type(4)));
typedef _Float16 f16x8 __attribute__((ext_vector_type(8)));
typedef float    f32x4 __attribute__((ext_vector_type(4)));

#if __has_builtin(__builtin_amdgcn_fdot2)
#define FDOT2(a, b, c) __builtin_amdgcn_fdot2((a), (b), (c), false)
#else
static __device__ __forceinline__ float FDOT2(f16x2 a, f16x2 b, float c) {
  return c + (float)a[0] * (float)b[0] + (float)a[1] * (float)b[1];
}
#endif

static __device__ __forceinline__ f16x2 asf16x2(unsigned u) {
  return __builtin_bit_cast(f16x2, u);
}

// sigmoid(x) = 1/(1+2^(-x*log2e));  tanh(x) = 2*sig(2x)-1
static __device__ __forceinline__ float fast_sig(float x) {
  float e = __builtin_amdgcn_exp2f(-1.44269504089f * x);
  return __builtin_amdgcn_rcpf(1.0f + e);
}
static __device__ __forceinline__ float fast_tanh(float x) {
  float e = __builtin_amdgcn_exp2f(-2.88539008178f * x);
  return 2.0f * __builtin_amdgcn_rcpf(1.0f + e) - 1.0f;
}

// LDS-only barrier (no vmcnt drain).  sched_barrier fences per rule #18.
#define BARRIER_LDS()                                   \
  __builtin_amdgcn_sched_barrier(0);                    \
  asm volatile("s_waitcnt lgkmcnt(0)" ::: "memory");    \
  __builtin_amdgcn_s_barrier();                         \
  __builtin_amdgcn_sched_barrier(0)

#define MFMA16(a, b, c) __builtin_amdgcn_mfma_f32_16x16x32_f16((a), (b), (c), 0, 0, 0)

// ---------------------------------------------------------------------------
// Kernel 1: xg[m][col], col = dir*512 + unit*4 + gate  (gate 0=i 1=f 2=g 3=o)
//   value = x[m]·W_ih[grow] + b_ih[grow] + b_hh[grow], grow = gate*128+unit.
//   Unit-major interleave: recurrence thread t reads col t (one u16).
// ---------------------------------------------------------------------------
__global__ __launch_bounds__(256) void xg_gemm(
    const float* __restrict__ x,
    const float* __restrict__ Wf, const float* __restrict__ Wb,
    const float* __restrict__ bf_ih, const float* __restrict__ bf_hh,
    const float* __restrict__ bb_ih, const float* __restrict__ bb_hh,
    f16* __restrict__ xg)
{
  __shared__ f16 xs[128][136];   // +8 f16 pad
  __shared__ f16 wt[128][136];

  const int tid = threadIdx.x;
  const int m0  = blockIdx.y * 128;
  const int n0  = blockIdx.x * 128;

  const float* Wsrc; const float* bih; const float* bhh; int nb; size_t dbase;
  if (n0 < 512) { Wsrc = Wf; bih = bf_ih; bhh = bf_hh; nb = n0;       dbase = 0; }
  else          { Wsrc = Wb; bih = bb_ih; bhh = bb_hh; nb = n0 - 512; dbase = 512; }

  const int w  = tid >> 6;
  const int l  = tid & 63;
  const int lr = l & 15;
  const int lk = (l >> 4) * 8;

  f32x4 acc[2][8] = {};

  #pragma unroll
  for (int kh = 0; kh < 2; ++kh) {
    #pragma unroll
    for (int it = 0; it < 16; ++it) {
      int idx = it * 256 + tid;
      int row = idx >> 5, c4 = idx & 31;
      float4 v = *(const float4*)&x[(size_t)(m0 + row) * I_ + kh * 128 + c4 * 4];
      f16x4 h4 = { (f16)v.x, (f16)v.y, (f16)v.z, (f16)v.w };
      *(f16x4*)&xs[row][c4 * 4] = h4;
    }
    #pragma unroll
    for (int it = 0; it < 16; ++it) {
      int idx = it * 256 + tid;
      int row = idx >> 5, c4 = idx & 31;
      float4 v = *(const float4*)&Wsrc[(size_t)(nb + row) * I_ + kh * 128 + c4 * 4];
      f16x4 h4 = { (f16)v.x, (f16)v.y, (f16)v.z, (f16)v.w };
      *(f16x4*)&wt[row][c4 * 4] = h4;
    }
    __syncthreads();

    #pragma unroll
    for (int ks = 0; ks < 4; ++ks) {
      int kk = ks * 32 + lk;
      f16x8 a0 = *(const f16x8*)&xs[w * 32 + lr][kk];
      f16x8 a1 = *(const f16x8*)&xs[w * 32 + 16 + lr][kk];
      #pragma unroll
      for (int nt = 0; nt < 8; ++nt) {
        f16x8 bf = *(const f16x8*)&wt[nt * 16 + lr][kk];
        acc[0][nt] = MFMA16(a0, bf, acc[0][nt]);
        acc[1][nt] = MFMA16(a1, bf, acc[1][nt]);
      }
    }
    __syncthreads();
  }

  // epilogue: D row = (l>>4)*4 + r, col = l&15; scatter to unit-major layout
  #pragma unroll
  for (int mt = 0; mt < 2; ++mt) {
    #pragma unroll
    for (int nt = 0; nt < 8; ++nt) {
      int nloc = nt * 16 + lr;
      int grow = nb + nloc;                 // gate-row within dir, 0..511
      int gate = grow >> 7, unit = grow & 127;
      size_t col = dbase + (size_t)unit * 4 + gate;
      float bias = bih[grow] + bhh[grow];
      #pragma unroll
      for (int r = 0; r < 4; ++r) {
        int m = m0 + w * 32 + mt * 16 + (l >> 4) * 4 + r;
        xg[(size_t)m * 1024 + col] = (f16)(acc[mt][nt][r] + bias);
      }
    }
  }
}

// ---------------------------------------------------------------------------
// Kernel 2: recurrence, 8 gate-rows per thread (minimum LDS broadcast).
//   64 WGs x 512 thr (8 waves).  Thread t: grp = t>>3, sl = t&7.
//   Owns K-slice [sl*16, sl*16+16) of logical rows grp*8 + (j^sl), j=0..7
//   (xor indexing -> reduced row grp*8+sl lands in p[0] with 7 static shfls).
//   Logical row r = unit*4 + gate  (unit = r>>2, gate = r&3: i,f,g,o).
//   Weights: 8x8 f16x2 = 64 words/thread, VGPR-resident at (512,1).
//   h-read: 32 B/thread = 2 ds_read_b128 -> 16 KB/CU/step (was 64).
//   Gate combine: unit's 4 rows sit in lanes t..t^3 -> 3 static shfl_xor.
//   All lanes compute c,h uniformly; gate-0 lane's is the real one, writes.
//   ONE LDS-only barrier per step; global xg prefetch depth 2, direct out.
// ---------------------------------------------------------------------------
__global__ __launch_bounds__(512, 1) void birnn_rec(
    const f16* __restrict__ xg,
    const float* __restrict__ Wfhh, const float* __restrict__ Wbhh,
    const int* __restrict__ lengths,
    float* __restrict__ out)
{
  const int tid = threadIdx.x;
  const int sl  = tid & 7;      // K-slice
  const int grp = tid >> 3;     // row group (8 rows)
  const int uu  = tid >> 2;     // unit of owned row
  const int gg  = tid & 3;      // gate of owned row
  const int dir = blockIdx.x >> 5;
  const int b   = blockIdx.x & 31;
  const float* Whh = dir ? Wbhh : Wfhh;
  const int L   = lengths[b];

  // wrg[j][k]: logical row grp*8+(j^sl), cols sl*16 + 2k..2k+1
  unsigned wrg[8][8];
  #pragma unroll
  for (int j = 0; j < 8; ++j) {
    int lr = grp * 8 + (j ^ sl);
    const float* src = &Whh[(size_t)((lr & 3) * 128 + (lr >> 2)) * H_ + sl * 16];
    #pragma unroll
    for (int k4 = 0; k4 < 4; ++k4) {
      float4 v = *(const float4*)&src[k4 * 4];
      wrg[j][2 * k4]     = __builtin_bit_cast(unsigned, (f16x2){ (f16)v.x, (f16)v.y });
      wrg[j][2 * k4 + 1] = __builtin_bit_cast(unsigned, (f16x2){ (f16)v.z, (f16)v.w });
    }
  }

  __shared__ __align__(16) f16 hbuf[2][128];
  if (tid < 128) hbuf[0][tid] = (f16)0.0f;
  float c = 0.0f;
  __syncthreads();

  auto rowof = [&](int t) -> size_t {
    int it = t;
    if (dir) it = (t < L) ? (L - 1 - t) : t;
    return (size_t)(b * T_ + it) * 1024 + (size_t)dir * 512 + (size_t)tid;
  };

  // depth-2 xg prefetch (named slots)
  f16 pa = xg[rowof(0)];
  f16 pb = xg[rowof(1)];

  const float bscale = (gg == 2) ? 2.0f : 1.0f;   // gate g -> tanh = 2*sig(2x)-1
  const float bmul   = (gg == 2) ? 2.0f : 1.0f;
  const float badd   = (gg == 2) ? -1.0f : 0.0f;
  const bool  writer = (gg == 0);

#define STEP(t, P, RB, WB)                                                   \
  {                                                                          \
    float xv = (float)(P);                                                   \
    if ((t) + 2 < T_) P = xg[rowof((t) + 2)];                                \
    uint4 hA = *(const uint4*)&hbuf[RB][sl * 16];                            \
    uint4 hB = *(const uint4*)&hbuf[RB][sl * 16 + 8];                        \
    float p[8] = { 0.f, 0.f, 0.f, 0.f, 0.f, 0.f, 0.f, 0.f };                 \
    _Pragma("unroll")                                                        \
    for (int j = 0; j < 8; ++j) {                                            \
      p[j] = FDOT2(asf16x2(hA.x), asf16x2(wrg[j][0]), p[j]);                 \
      p[j] = FDOT2(asf16x2(hA.y), asf16x2(wrg[j][1]), p[j]);                 \
      p[j] = FDOT2(asf16x2(hA.z), asf16x2(wrg[j][2]), p[j]);                 \
      p[j] = FDOT2(asf16x2(hA.w), asf16x2(wrg[j][3]), p[j]);                 \
      p[j] = FDOT2(asf16x2(hB.x), asf16x2(wrg[j][4]), p[j]);                 \
      p[j] = FDOT2(asf16x2(hB.y), asf16x2(wrg[j][5]), p[j]);                 \
      p[j] = FDOT2(asf16x2(hB.z), asf16x2(wrg[j][6]), p[j]);                 \
      p[j] = FDOT2(asf16x2(hB.w), asf16x2(wrg[j][7]), p[j]);                 \
    }                                                                        \
    /* xor-indexed recursive halving: row grp*8+sl accumulates into p[0] */  \
    p[0] += __shfl_xor(p[1], 1, 64);                                         \
    p[2] += __shfl_xor(p[3], 1, 64);                                         \
    p[4] += __shfl_xor(p[5], 1, 64);                                         \
    p[6] += __shfl_xor(p[7], 1, 64);                                         \
    p[0] += __shfl_xor(p[2], 2, 64);                                         \
    p[4] += __shfl_xor(p[6], 2, 64);                                         \
    p[0] += __shfl_xor(p[4], 4, 64);                                         \
    float sum = p[0] + xv;                                                   \
    float act = fast_sig(bscale * sum) * bmul + badd;                        \
    float a1 = __shfl_xor(act, 1, 64);                                       \
    float a2 = __shfl_xor(act, 2, 64);                                       \
    float a3 = __shfl_xor(act, 3, 64);                                       \
    /* gate-0 lanes: act=i, a1=f, a2=g, a3=o; others compute garbage */      \
    c = a1 * c + act * a2;                                                   \
    float hval = a3 * fast_tanh(c);                                          \
    if (writer) {                                                            \
      hbuf[WB][uu] = (f16)hval;                                              \
      out[(size_t)(b * T_ + (t)) * 256 + dir * 128 + uu] = hval;             \
    }                                                                        \
    BARRIER_LDS();                                                           \
  }

  for (int tt = 0; tt < T_; tt += 2) {
    STEP(tt,     pa, 0, 1)
    STEP(tt + 1, pb, 1, 0)
  }
#undef STEP
}

// ---------------------------------------------------------------------------
extern "C" void kernel_launch(void* const* d_in, const int* in_sizes, int n_in,
                              void* d_out, int out_size, void* d_ws, size_t ws_size,
                              hipStream_t stream) {
  const float* x      = (const float*)d_in[0];
  const int*   lengths= (const int*)  d_in[1];
  const float* Wf_ih  = (const float*)d_in[2];
  const float* Wf_hh  = (const float*)d_in[3];
  const float* bf_ih  = (const float*)d_in[4];
  const float* bf_hh  = (const float*)d_in[5];
  const float* Wb_ih  = (const float*)d_in[6];
  const float* Wb_hh  = (const float*)d_in[7];
  const float* bb_ih  = (const float*)d_in[8];
  const float* bb_hh  = (const float*)d_in[9];
  float* out = (float*)d_out;
  f16*   xg  = (f16*)d_ws;   // needs B*T*1024*2 = 134,217,728 bytes

  (void)in_sizes; (void)n_in; (void)out_size; (void)ws_size;

  xg_gemm<<<dim3(8, 512), 256, 0, stream>>>(x, Wf_ih, Wb_ih,
                                            bf_ih, bf_hh, bb_ih, bb_hh, xg);
  birnn_rec<<<dim3(64), 512, 0, stream>>>(xg, Wf_hh, Wb_hh, lengths, out);
}

// Round 11
// 1219.668 us; speedup vs baseline: 1.6002x; 1.1483x over previous
//
#include <hip/hip_runtime.h>
#include <hip/hip_fp16.h>

#define B_  32
#define T_  2048
#define I_  256
#define H_  128

typedef _Float16 f16;
typedef _Float16 f16x2 __attribute__((ext_vector_type(2)));
typedef _Float16 f16x4 __attribute__((ext_vector_type(4)));
typedef _Float16 f16x8 __attribute__((ext_vector_type(8)));
typedef float    f32x4 __attribute__((ext_vector_type(4)));

#if __has_builtin(__builtin_amdgcn_fdot2)
#define FDOT2(a, b, c) __builtin_amdgcn_fdot2((a), (b), (c), false)
#else
static __device__ __forceinline__ float FDOT2(f16x2 a, f16x2 b, float c) {
  return c + (float)a[0] * (float)b[0] + (float)a[1] * (float)b[1];
}
#endif

static __device__ __forceinline__ f16x2 asf16x2(unsigned u) {
  return __builtin_bit_cast(f16x2, u);
}

// Cross-lane via DPP quad_perm (VALU pipe -- NOT the DS pipe like shfl/bpermute)
//   xor1: [1,0,3,2]=0xB1   xor2: [2,3,0,1]=0x4E   xor3: [3,2,1,0]=0x1B
#define DPPF(x, ctrl)                                                      \
  __builtin_bit_cast(float, __builtin_amdgcn_mov_dpp(                      \
      __builtin_bit_cast(int, (x)), (ctrl), 0xF, 0xF, true))

static __device__ __forceinline__ float fast_sig(float x) {
  float e = __builtin_amdgcn_exp2f(-1.44269504089f * x);
  return __builtin_amdgcn_rcpf(1.0f + e);
}
static __device__ __forceinline__ float fast_tanh(float x) {
  float e = __builtin_amdgcn_exp2f(-2.88539008178f * x);
  return 2.0f * __builtin_amdgcn_rcpf(1.0f + e) - 1.0f;
}

// LDS-only barrier (no vmcnt drain).  sched_barrier fences per rule #18.
#define BARRIER_LDS()                                   \
  __builtin_amdgcn_sched_barrier(0);                    \
  asm volatile("s_waitcnt lgkmcnt(0)" ::: "memory");    \
  __builtin_amdgcn_s_barrier();                         \
  __builtin_amdgcn_sched_barrier(0)

#define MFMA16(a, b, c) __builtin_amdgcn_mfma_f32_16x16x32_f16((a), (b), (c), 0, 0, 0)

// ---------------------------------------------------------------------------
// Kernel 1: xg[m][col], col = dir*512 + unit*4 + gate  (gate 0=i 1=f 2=g 3=o)
//   value = x[m]·W_ih[grow] + b_ih[grow] + b_hh[grow], grow = gate*128+unit.
//   (unchanged from round 9)
// ---------------------------------------------------------------------------
__global__ __launch_bounds__(256) void xg_gemm(
    const float* __restrict__ x,
    const float* __restrict__ Wf, const float* __restrict__ Wb,
    const float* __restrict__ bf_ih, const float* __restrict__ bf_hh,
    const float* __restrict__ bb_ih, const float* __restrict__ bb_hh,
    f16* __restrict__ xg)
{
  __shared__ f16 xs[128][136];   // +8 f16 pad
  __shared__ f16 wt[128][136];

  const int tid = threadIdx.x;
  const int m0  = blockIdx.y * 128;
  const int n0  = blockIdx.x * 128;

  const float* Wsrc; const float* bih; const float* bhh; int nb; size_t dbase;
  if (n0 < 512) { Wsrc = Wf; bih = bf_ih; bhh = bf_hh; nb = n0;       dbase = 0; }
  else          { Wsrc = Wb; bih = bb_ih; bhh = bb_hh; nb = n0 - 512; dbase = 512; }

  const int w  = tid >> 6;
  const int l  = tid & 63;
  const int lr = l & 15;
  const int lk = (l >> 4) * 8;

  f32x4 acc[2][8] = {};

  #pragma unroll
  for (int kh = 0; kh < 2; ++kh) {
    #pragma unroll
    for (int it = 0; it < 16; ++it) {
      int idx = it * 256 + tid;
      int row = idx >> 5, c4 = idx & 31;
      float4 v = *(const float4*)&x[(size_t)(m0 + row) * I_ + kh * 128 + c4 * 4];
      f16x4 h4 = { (f16)v.x, (f16)v.y, (f16)v.z, (f16)v.w };
      *(f16x4*)&xs[row][c4 * 4] = h4;
    }
    #pragma unroll
    for (int it = 0; it < 16; ++it) {
      int idx = it * 256 + tid;
      int row = idx >> 5, c4 = idx & 31;
      float4 v = *(const float4*)&Wsrc[(size_t)(nb + row) * I_ + kh * 128 + c4 * 4];
      f16x4 h4 = { (f16)v.x, (f16)v.y, (f16)v.z, (f16)v.w };
      *(f16x4*)&wt[row][c4 * 4] = h4;
    }
    __syncthreads();

    #pragma unroll
    for (int ks = 0; ks < 4; ++ks) {
      int kk = ks * 32 + lk;
      f16x8 a0 = *(const f16x8*)&xs[w * 32 + lr][kk];
      f16x8 a1 = *(const f16x8*)&xs[w * 32 + 16 + lr][kk];
      #pragma unroll
      for (int nt = 0; nt < 8; ++nt) {
        f16x8 bf = *(const f16x8*)&wt[nt * 16 + lr][kk];
        acc[0][nt] = MFMA16(a0, bf, acc[0][nt]);
        acc[1][nt] = MFMA16(a1, bf, acc[1][nt]);
      }
    }
    __syncthreads();
  }

  // epilogue: D row = (l>>4)*4 + r, col = l&15; scatter to unit-major layout
  #pragma unroll
  for (int mt = 0; mt < 2; ++mt) {
    #pragma unroll
    for (int nt = 0; nt < 8; ++nt) {
      int nloc = nt * 16 + lr;
      int grow = nb + nloc;                 // gate-row within dir, 0..511
      int gate = grow >> 7, unit = grow & 127;
      size_t col = dbase + (size_t)unit * 4 + gate;
      float bias = bih[grow] + bhh[grow];
      #pragma unroll
      for (int r = 0; r < 4; ++r) {
        int m = m0 + w * 32 + mt * 16 + (l >> 4) * 4 + r;
        xg[(size_t)m * 1024 + col] = (f16)(acc[mt][nt][r] + bias);
      }
    }
  }
}

// ---------------------------------------------------------------------------
// Kernel 2: recurrence -- R9 structure with ALL shuffles moved off the DS pipe.
//   64 WGs x 512 thr (8 waves).  Lane l of wave w:
//     sl = (l&3)|((l>>5)<<2)   K-slice (bits l0,l1,l5) -> cols [sl*16,+16)
//     g  = w*8 + ((l>>2)&7)    row group (8 logical rows g*8..g*8+7)
//     owns rows g*8+(j^sl), j=0..7 (xor-indexed); owned row r = g*8+sl
//     r = unit*4+gate: unit uu = r>>2, gate gg = r&3 (== l&3)
//   K-reduce levels = sl bits = lane bits 0,1,5:
//     xor1, xor2 -> quad_perm DPP (VALU);  xor32 -> one ds_bpermute.
//   Gate gather: unit's 4 gates live in the lane QUAD -> xor1/2/3 quad_perm.
//   DS ops/thread/step: 2 ds_read_b128 + 1 bpermute  (round 9 had 12).
//   All lanes compute c,h convergently; gate-0 lane writes h + out.
//   ONE LDS-only barrier per step; depth-2 global xg prefetch.
// ---------------------------------------------------------------------------
__global__ __launch_bounds__(512, 1) void birnn_rec(
    const f16* __restrict__ xg,
    const float* __restrict__ Wfhh, const float* __restrict__ Wbhh,
    const int* __restrict__ lengths,
    float* __restrict__ out)
{
  const int tid = threadIdx.x;
  const int w   = tid >> 6;
  const int l   = tid & 63;
  const int sl  = (l & 3) | ((l >> 5) << 2);   // K-slice 0..7
  const int g   = w * 8 + ((l >> 2) & 7);      // row group 0..63
  const int r   = g * 8 + sl;                  // owned logical row 0..511
  const int uu  = r >> 2;                      // unit 0..127
  const int gg  = r & 3;                       // gate (== l&3)
  const int dir = blockIdx.x >> 5;
  const int b   = blockIdx.x & 31;
  const float* Whh = dir ? Wbhh : Wfhh;
  const int L   = lengths[b];

  // wrg[j][k]: logical row g*8+(j^sl), cols sl*16 + 2k..2k+1
  unsigned wrg[8][8];
  #pragma unroll
  for (int j = 0; j < 8; ++j) {
    int lrow = g * 8 + (j ^ sl);
    const float* src = &Whh[(size_t)((lrow & 3) * 128 + (lrow >> 2)) * H_ + sl * 16];
    #pragma unroll
    for (int k4 = 0; k4 < 4; ++k4) {
      float4 v = *(const float4*)&src[k4 * 4];
      wrg[j][2 * k4]     = __builtin_bit_cast(unsigned, (f16x2){ (f16)v.x, (f16)v.y });
      wrg[j][2 * k4 + 1] = __builtin_bit_cast(unsigned, (f16x2){ (f16)v.z, (f16)v.w });
    }
  }

  __shared__ __align__(16) f16 hbuf[2][128];
  if (tid < 128) hbuf[0][tid] = (f16)0.0f;
  float c = 0.0f;
  __syncthreads();

  auto rowof = [&](int t) -> size_t {
    int it = t;
    if (dir) it = (t < L) ? (L - 1 - t) : t;
    return (size_t)(b * T_ + it) * 1024 + (size_t)dir * 512 + (size_t)r;
  };

  // depth-2 xg prefetch (named slots)
  f16 pa = xg[rowof(0)];
  f16 pb = xg[rowof(1)];

  const float bscale = (gg == 2) ? 2.0f : 1.0f;   // gate g -> tanh = 2*sig(2x)-1
  const float bmul   = (gg == 2) ? 2.0f : 1.0f;
  const float badd   = (gg == 2) ? -1.0f : 0.0f;
  const bool  writer = (gg == 0);

#define STEP(t, P, RB, WB)                                                   \
  {                                                                          \
    float xv = (float)(P);                                                   \
    if ((t) + 2 < T_) P = xg[rowof((t) + 2)];                                \
    uint4 hA = *(const uint4*)&hbuf[RB][sl * 16];                            \
    uint4 hB = *(const uint4*)&hbuf[RB][sl * 16 + 8];                        \
    float p[8] = { 0.f, 0.f, 0.f, 0.f, 0.f, 0.f, 0.f, 0.f };                 \
    _Pragma("unroll")                                                        \
    for (int j = 0; j < 8; ++j) {                                            \
      p[j] = FDOT2(asf16x2(hA.x), asf16x2(wrg[j][0]), p[j]);                 \
      p[j] = FDOT2(asf16x2(hA.y), asf16x2(wrg[j][1]), p[j]);                 \
      p[j] = FDOT2(asf16x2(hA.z), asf16x2(wrg[j][2]), p[j]);                 \
      p[j] = FDOT2(asf16x2(hA.w), asf16x2(wrg[j][3]), p[j]);                 \
      p[j] = FDOT2(asf16x2(hB.x), asf16x2(wrg[j][4]), p[j]);                 \
      p[j] = FDOT2(asf16x2(hB.y), asf16x2(wrg[j][5]), p[j]);                 \
      p[j] = FDOT2(asf16x2(hB.z), asf16x2(wrg[j][6]), p[j]);                 \
      p[j] = FDOT2(asf16x2(hB.w), asf16x2(wrg[j][7]), p[j]);                 \
    }                                                                        \
    /* K-reduce: sl bits {0,1} via quad_perm DPP, bit {5} via one shfl */    \
    p[0] += DPPF(p[1], 0xB1);                                                \
    p[2] += DPPF(p[3], 0xB1);                                                \
    p[4] += DPPF(p[5], 0xB1);                                                \
    p[6] += DPPF(p[7], 0xB1);                                                \
    p[0] += DPPF(p[2], 0x4E);                                                \
    p[4] += DPPF(p[6], 0x4E);                                                \
    p[0] += __shfl_xor(p[4], 32, 64);                                        \
    float sum = p[0] + xv;                                                   \
    float act = fast_sig(bscale * sum) * bmul + badd;                        \
    /* gate gather within the lane quad (unit's i,f,g,o) -- pure DPP */      \
    float a1 = DPPF(act, 0xB1);                                              \
    float a2 = DPPF(act, 0x4E);                                              \
    float a3 = DPPF(act, 0x1B);                                              \
    /* gate-0 lanes: act=i, a1=f, a2=g, a3=o; others compute garbage */      \
    c = a1 * c + act * a2;                                                   \
    float hval = a3 * fast_tanh(c);                                          \
    if (writer) {                                                            \
      hbuf[WB][uu] = (f16)hval;                                              \
      out[(size_t)(b * T_ + (t)) * 256 + dir * 128 + uu] = hval;             \
    }                                                                        \
    BARRIER_LDS();                                                           \
  }

  for (int tt = 0; tt < T_; tt += 2) {
    STEP(tt,     pa, 0, 1)
    STEP(tt + 1, pb, 1, 0)
  }
#undef STEP
}

// ---------------------------------------------------------------------------
extern "C" void kernel_launch(void* const* d_in, const int* in_sizes, int n_in,
                              void* d_out, int out_size, void* d_ws, size_t ws_size,
                              hipStream_t stream) {
  const float* x      = (const float*)d_in[0];
  const int*   lengths= (const int*)  d_in[1];
  const float* Wf_ih  = (const float*)d_in[2];
  const float* Wf_hh  = (const float*)d_in[3];
  const float* bf_ih  = (const float*)d_in[4];
  const float* bf_hh  = (const float*)d_in[5];
  const float* Wb_ih  = (const float*)d_in[6];
  const float* Wb_hh  = (const float*)d_in[7];
  const float* bb_ih  = (const float*)d_in[8];
  const float* bb_hh  = (const float*)d_in[9];
  float* out = (float*)d_out;
  f16*   xg  = (f16*)d_ws;   // needs B*T*1024*2 = 134,217,728 bytes

  (void)in_sizes; (void)n_in; (void)out_size; (void)ws_size;

  xg_gemm<<<dim3(8, 512), 256, 0, stream>>>(x, Wf_ih, Wb_ih,
                                            bf_ih, bf_hh, bb_ih, bb_hh, xg);
  birnn_rec<<<dim3(64), 512, 0, stream>>>(xg, Wf_hh, Wb_hh, lengths, out);
}